// Round 6
// baseline (171.027 us; speedup 1.0000x reference)
//
#include <hip/hip_runtime.h>
#include <stdint.h>

#define M_DIM 1024
#define K_DIM 4096
#define N_DIM 11008
#define NPACK 1376
#define NGROUPS 32

#define BM 256
#define BN 256
#define BK 64
#define NT (K_DIM / BK)     // 64
#define ATILE (BM * BK)
#define BTILE (BN * BK)

typedef __attribute__((ext_vector_type(4))) float f32x4;
typedef __attribute__((ext_vector_type(8))) _Float16 f16x8;
typedef __attribute__((ext_vector_type(2))) _Float16 h2;

static __device__ __forceinline__ unsigned int swz(unsigned int r) {
  return (r ^ (r >> 3)) & 7u;
}

// prepass: x fp32 -> fp16 (exact: x was originally fp16)
__global__ __launch_bounds__(256)
void conv_x(const float* __restrict__ X, unsigned short* __restrict__ XH) {
  const size_t i = ((size_t)blockIdx.x * 256 + threadIdx.x) * 8;
  const float4 a = *(const float4*)(X + i);
  const float4 b = *(const float4*)(X + i + 4);
  uint4 o;
  o.x = __builtin_bit_cast(unsigned int, __builtin_amdgcn_cvt_pkrtz(a.x, a.y));
  o.y = __builtin_bit_cast(unsigned int, __builtin_amdgcn_cvt_pkrtz(a.z, a.w));
  o.z = __builtin_bit_cast(unsigned int, __builtin_amdgcn_cvt_pkrtz(b.x, b.y));
  o.w = __builtin_bit_cast(unsigned int, __builtin_amdgcn_cvt_pkrtz(b.z, b.w));
  *(uint4*)(XH + i) = o;
}

// ---------------- 8-phase kernel (PRE path) ----------------

#define READ_A4(BASE, KK, MH)                                                  \
  _Pragma("unroll") for (int m_ = 0; m_ < 4; ++m_)                             \
      af[m_] = *(const f16x8*)((const char*)(BASE) + aoff[KK][(MH)*4 + m_]);

#define READ_B4(BASE, KK)                                                      \
  _Pragma("unroll") for (int n_ = 0; n_ < 4; ++n_)                             \
      bfv[n_] = *(const f16x8*)((const char*)(BASE) + boff[KK][n_]);

#define MFMA16(MH)                                                             \
  _Pragma("unroll") for (int m_ = 0; m_ < 4; ++m_)                             \
  _Pragma("unroll") for (int n_ = 0; n_ < 4; ++n_)                             \
      acc[(MH)*4 + m_][n_] = __builtin_amdgcn_mfma_f32_16x16x32_f16(           \
          af[m_], bfv[n_], acc[(MH)*4 + m_][n_], 0, 0, 0);

#define DEQ2(BDST, QWQ, J0)                                                    \
  _Pragma("unroll") for (int j_ = (J0); j_ < (J0) + 2; ++j_) {                 \
    const int sh_ = SH[j_];                                                    \
    const unsigned q01_ = ((QWQ[0] >> sh_) & 15u) |                            \
        (((QWQ[1] >> sh_) & 15u) << 16) | 0x64006400u;                         \
    const unsigned q23_ = ((QWQ[2] >> sh_) & 15u) |                            \
        (((QWQ[3] >> sh_) & 15u) << 16) | 0x64006400u;                         \
    const h2 w01_ = (__builtin_bit_cast(h2, q01_) -                            \
        __builtin_bit_cast(h2, zz[j_])) * __builtin_bit_cast(h2, ss[j_]);      \
    const h2 w23_ = (__builtin_bit_cast(h2, q23_) -                            \
        __builtin_bit_cast(h2, zz[j_])) * __builtin_bit_cast(h2, ss[j_]);      \
    uint2 wv_;                                                                 \
    wv_.x = __builtin_bit_cast(unsigned, w01_);                                \
    wv_.y = __builtin_bit_cast(unsigned, w23_);                                \
    *(uint2*)((char*)(BDST) + woff[j_]) = wv_;                                 \
  }

#define GLDS2(DST, K0V, I0)                                                    \
  _Pragma("unroll") for (int i_ = (I0); i_ < (I0) + 2; ++i_) {                 \
    const int gb_ = i_ * 512 + wid * 64;                                       \
    const int g_ = gb_ + lane;                                                 \
    const unsigned r_ = (unsigned)(g_ >> 3), c_ = (unsigned)(g_ & 7);          \
    const unsigned short* gs_ =                                                \
        XH + (size_t)(row0 + r_) * K_DIM + (K0V) + ((c_ ^ swz(r_)) << 3);      \
    __builtin_amdgcn_global_load_lds(                                          \
        (const __attribute__((address_space(1))) void*)gs_,                    \
        (__attribute__((address_space(3))) void*)((DST) + gb_ * 8), 16, 0, 0); \
  }

#define LOADQW(DSTQ, KROW)                                                     \
  _Pragma("unroll") for (int i_ = 0; i_ < 4; ++i_)                             \
      DSTQ[i_] = (unsigned)QW[(size_t)((KROW) + dq_k + i_) * NPACK + p0 + dq_p];

#define PREP_LOAD(GRP)                                                         \
  qzv_n = (unsigned)QZ[(GRP) * NPACK + p0 + dq_p];                             \
  sv0_n = *(const float4*)(S + (size_t)(GRP) * N_DIM + n0 + dq_p * 8);         \
  sv1_n = *(const float4*)(S + (size_t)(GRP) * N_DIM + n0 + dq_p * 8 + 4);

#define PREP_CALC()                                                            \
  {                                                                            \
    const float svf_[8] = {sv0_n.x, sv0_n.y, sv0_n.z, sv0_n.w,                 \
                           sv1_n.x, sv1_n.y, sv1_n.z, sv1_n.w};                \
    _Pragma("unroll") for (int j_ = 0; j_ < 8; ++j_) {                         \
      const unsigned z_ = (qzv_n >> SH[j_]) & 15u;                             \
      zz[j_] = z_ * 0x10001u + 0x64006400u;                                    \
      ss[j_] = __builtin_bit_cast(unsigned,                                    \
          __builtin_amdgcn_cvt_pkrtz(svf_[j_], svf_[j_]));                     \
    }                                                                          \
  }

#define PHASE_TAIL()                                                           \
  __builtin_amdgcn_s_barrier();                                                \
  asm volatile("s_waitcnt lgkmcnt(0)" ::: "memory");                           \
  __builtin_amdgcn_sched_barrier(0);                                           \
  __builtin_amdgcn_s_setprio(1);

#define PHASE_END()                                                            \
  __builtin_amdgcn_s_setprio(0);                                               \
  __builtin_amdgcn_s_barrier();

__global__ __launch_bounds__(512, 2)
void awq_gemm8(const unsigned short* __restrict__ XH,
               const int* __restrict__ QW,
               const int* __restrict__ QZ,
               const float* __restrict__ S,
               const float* __restrict__ BIAS,
               float* __restrict__ OUT)
{
  __shared__ unsigned short Alds[2][ATILE];
  __shared__ unsigned short Blds[2][BTILE];

  const int tid  = threadIdx.x;
  const int lane = tid & 63;
  const int wid  = tid >> 6;
  const int wr   = wid >> 2;
  const int wc   = wid & 3;
  const int l15  = lane & 15;
  const int l4   = lane >> 4;

  const int row0 = blockIdx.y * BM;
  const int n0   = blockIdx.x * BN;
  const int p0   = n0 >> 3;

  const int dq_p = tid & 31;
  const int dq_k = (tid >> 5) << 2;

  const int SH[8] = {0, 16, 4, 20, 8, 24, 12, 28};

  // hoisted LDS byte offsets (lane-dependent, loop-invariant)
  unsigned aoff[2][8], boff[2][4], woff[8];
  #pragma unroll
  for (int kk = 0; kk < 2; ++kk) {
    #pragma unroll
    for (int m = 0; m < 8; ++m) {
      const unsigned r = (unsigned)(wr * 128 + m * 16 + l15);
      aoff[kk][m] = r * 128 + (((unsigned)(kk * 4 + l4) ^ swz(r)) << 4);
    }
    #pragma unroll
    for (int n = 0; n < 4; ++n) {
      const unsigned r = (unsigned)(wc * 64 + n * 16 + l15);
      boff[kk][n] = r * 128 + (((unsigned)(kk * 4 + l4) ^ swz(r)) << 4);
    }
  }
  #pragma unroll
  for (int j = 0; j < 8; ++j) {
    const unsigned nn = (unsigned)(dq_p * 8 + j);
    woff[j] = nn * 128 + (((unsigned)(dq_k * 2)) ^ (swz(nn) << 4));
  }

  unsigned short* const A0 = &Alds[0][0];
  unsigned short* const A1 = &Alds[1][0];
  unsigned short* const B0 = &Blds[0][0];
  unsigned short* const B1 = &Blds[1][0];

  f32x4 acc[8][4];
  #pragma unroll
  for (int i = 0; i < 8; ++i)
    #pragma unroll
    for (int j = 0; j < 4; ++j)
      acc[i][j] = (f32x4){0.f, 0.f, 0.f, 0.f};

  f16x8 af[4], bfv[4];
  unsigned qwE[4], qwO[4];
  unsigned zz[8], ss[8];
  unsigned qzv_n;
  float4 sv0_n, sv1_n;

  // ---------------- prologue: stage tile 0 into buf0 ----------------
  {
    unsigned qtmp[4];
    LOADQW(qtmp, 0);
    PREP_LOAD(0);
    PREP_CALC();
    GLDS2(A0, 0, 0);
    GLDS2(A0, 0, 2);
    DEQ2(B0, qtmp, 0); DEQ2(B0, qtmp, 2); DEQ2(B0, qtmp, 4); DEQ2(B0, qtmp, 6);
    LOADQW(qwE, BK);  // qw(tile 1)
  }
  asm volatile("s_waitcnt vmcnt(0) lgkmcnt(0)" ::: "memory");
  __builtin_amdgcn_s_barrier();

  // ---------------- main loop: iters I=0..30, tiles 0..61 ----------------
  for (int I = 0; I < 31; ++I) {
    const int t = 2 * I;

    // ===== EVEN tile t: compute buf0, stage t+1 -> buf1 =====
    // ph1
    READ_B4(B0, 0);
    READ_A4(A0, 0, 0);
    GLDS2(A1, (t + 1) * BK, 0);
    __builtin_amdgcn_sched_barrier(0);
    LOADQW(qwO, (t + 2) * BK);
    DEQ2(B1, qwE, 0);
    PHASE_TAIL(); MFMA16(0); PHASE_END();
    // ph2
    READ_A4(A0, 0, 1);
    GLDS2(A1, (t + 1) * BK, 2);
    __builtin_amdgcn_sched_barrier(0);
    DEQ2(B1, qwE, 2);
    PHASE_TAIL(); MFMA16(1); PHASE_END();
    // ph3
    READ_B4(B0, 1);
    READ_A4(A0, 1, 0);
    DEQ2(B1, qwE, 4);
    PHASE_TAIL(); MFMA16(0); PHASE_END();
    // ph4 (tile boundary: counted vmcnt — glds(t+1) are 4 oldest after qw)
    READ_A4(A0, 1, 1);
    PREP_LOAD(I + 1);
    DEQ2(B1, qwE, 6);
    __builtin_amdgcn_s_barrier();
    asm volatile("s_waitcnt lgkmcnt(0)" ::: "memory");
    __builtin_amdgcn_sched_barrier(0);
    __builtin_amdgcn_s_setprio(1);
    MFMA16(1);
    __builtin_amdgcn_s_setprio(0);
    asm volatile("s_waitcnt vmcnt(3)" ::: "memory");  // qz+s×2 may stay in flight
    __builtin_amdgcn_s_barrier();

    // ===== ODD tile t+1: compute buf1, stage t+2 -> buf0 =====
    // ph5
    PREP_CALC();   // zz/ss <- group I+1 (loads from even-ph4; compiler waits)
    READ_B4(B1, 0);
    READ_A4(A1, 0, 0);
    GLDS2(A0, (t + 2) * BK, 0);
    __builtin_amdgcn_sched_barrier(0);
    LOADQW(qwE, (t + 3) * BK);   // t+3 <= 63 for I <= 30
    DEQ2(B0, qwO, 0);
    PHASE_TAIL(); MFMA16(0); PHASE_END();
    // ph6
    READ_A4(A1, 0, 1);
    GLDS2(A0, (t + 2) * BK, 2);
    __builtin_amdgcn_sched_barrier(0);
    DEQ2(B0, qwO, 2);
    PHASE_TAIL(); MFMA16(1); PHASE_END();
    // ph7
    READ_B4(B1, 1);
    READ_A4(A1, 1, 0);
    DEQ2(B0, qwO, 4);
    PHASE_TAIL(); MFMA16(0); PHASE_END();
    // ph8 (tile boundary)
    READ_A4(A1, 1, 1);
    DEQ2(B0, qwO, 6);
    __builtin_amdgcn_s_barrier();
    asm volatile("s_waitcnt lgkmcnt(0)" ::: "memory");
    __builtin_amdgcn_sched_barrier(0);
    __builtin_amdgcn_s_setprio(1);
    MFMA16(1);
    __builtin_amdgcn_s_setprio(0);
    asm volatile("s_waitcnt vmcnt(0)" ::: "memory");  // glds(t+2) are newest
    __builtin_amdgcn_s_barrier();
  }

  // ===== tile 62: compute buf0, stage 63 -> buf1 (qwE = qw(63), zz/ss = grp 31) =====
  READ_B4(B0, 0);
  READ_A4(A0, 0, 0);
  GLDS2(A1, 63 * BK, 0);
  DEQ2(B1, qwE, 0);
  PHASE_TAIL(); MFMA16(0); PHASE_END();
  READ_A4(A0, 0, 1);
  GLDS2(A1, 63 * BK, 2);
  DEQ2(B1, qwE, 2);
  PHASE_TAIL(); MFMA16(1); PHASE_END();
  READ_B4(B0, 1);
  READ_A4(A0, 1, 0);
  DEQ2(B1, qwE, 4);
  PHASE_TAIL(); MFMA16(0); PHASE_END();
  READ_A4(A0, 1, 1);
  DEQ2(B1, qwE, 6);
  __builtin_amdgcn_s_barrier();
  asm volatile("s_waitcnt lgkmcnt(0)" ::: "memory");
  __builtin_amdgcn_sched_barrier(0);
  __builtin_amdgcn_s_setprio(1);
  MFMA16(1);
  __builtin_amdgcn_s_setprio(0);
  asm volatile("s_waitcnt vmcnt(0)" ::: "memory");
  __builtin_amdgcn_s_barrier();

  // ===== tile 63: compute buf1, no staging =====
  READ_B4(B1, 0);
  READ_A4(A1, 0, 0);
  asm volatile("s_waitcnt lgkmcnt(0)" ::: "memory");
  __builtin_amdgcn_sched_barrier(0);
  MFMA16(0);
  READ_A4(A1, 0, 1);
  asm volatile("s_waitcnt lgkmcnt(0)" ::: "memory");
  __builtin_amdgcn_sched_barrier(0);
  MFMA16(1);
  READ_B4(B1, 1);
  READ_A4(A1, 1, 0);
  asm volatile("s_waitcnt lgkmcnt(0)" ::: "memory");
  __builtin_amdgcn_sched_barrier(0);
  MFMA16(0);
  READ_A4(A1, 1, 1);
  asm volatile("s_waitcnt lgkmcnt(0)" ::: "memory");
  __builtin_amdgcn_sched_barrier(0);
  MFMA16(1);

  // ---------------- epilogue: + bias, store fp32 ----------------
  #pragma unroll
  for (int n = 0; n < 4; ++n) {
    const int col = n0 + wc * 64 + n * 16 + l15;
    const float bz = BIAS[col];
    #pragma unroll
    for (int m = 0; m < 8; ++m) {
      const int rbase = row0 + wr * 128 + m * 16 + l4 * 4;
      #pragma unroll
      for (int r = 0; r < 4; ++r) {
        OUT[(size_t)(rbase + r) * N_DIM + col] = acc[m][n][r] + bz;
      }
    }
  }
}

// ---------------- fallback (round-5 structure, fp32 x, no workspace) ----------------
__global__ __launch_bounds__(512, 2)
void awq_gemm_fb(const float* __restrict__ XF,
                 const int* __restrict__ QW,
                 const int* __restrict__ QZ,
                 const float* __restrict__ S,
                 const float* __restrict__ BIAS,
                 float* __restrict__ OUT)
{
  __shared__ unsigned short Alds[2][ATILE];
  __shared__ unsigned short Blds[2][BTILE];

  const int tid  = threadIdx.x;
  const int lane = tid & 63;
  const int wid  = tid >> 6;
  const int wr   = wid >> 2;
  const int wc   = wid & 3;
  const int l15  = lane & 15;
  const int l4   = lane >> 4;

  const int row0 = blockIdx.y * BM;
  const int n0   = blockIdx.x * BN;
  const int p0   = n0 >> 3;

  const int dq_p = tid & 31;
  const int dq_k = (tid >> 5) << 2;

  f32x4 acc[8][4];
  #pragma unroll
  for (int i = 0; i < 8; ++i)
    #pragma unroll
    for (int j = 0; j < 4; ++j)
      acc[i][j] = (f32x4){0.f, 0.f, 0.f, 0.f};

  const int SH[8] = {0, 16, 4, 20, 8, 24, 12, 28};
  unsigned int zz[8], ss[8];

  auto stageA = [&](int buf, int k0) {
    #pragma unroll
    for (int i = 0; i < 4; ++i) {
      const int g = i * 512 + tid;
      const unsigned int r = (unsigned)(g >> 3), c = (unsigned)(g & 7);
      const float* src = XF + (size_t)(row0 + r) * K_DIM + k0 + (c << 3);
      const float4 v0 = *(const float4*)src;
      const float4 v1 = *(const float4*)(src + 4);
      uint4 o;
      o.x = __builtin_bit_cast(unsigned int, __builtin_amdgcn_cvt_pkrtz(v0.x, v0.y));
      o.y = __builtin_bit_cast(unsigned int, __builtin_amdgcn_cvt_pkrtz(v0.z, v0.w));
      o.z = __builtin_bit_cast(unsigned int, __builtin_amdgcn_cvt_pkrtz(v1.x, v1.y));
      o.w = __builtin_bit_cast(unsigned int, __builtin_amdgcn_cvt_pkrtz(v1.z, v1.w));
      *(uint4*)((char*)&Alds[buf][0] + r * 128 + ((c ^ swz(r)) << 4)) = o;
    }
  };

  auto prepGroup = [&](int grp) {
    const unsigned int qzv = (unsigned int)QZ[grp * NPACK + p0 + dq_p];
    const float* sp = S + (size_t)grp * N_DIM + n0 + dq_p * 8;
    const float4 sv0 = *(const float4*)sp;
    const float4 sv1 = *(const float4*)(sp + 4);
    const float svf[8] = {sv0.x, sv0.y, sv0.z, sv0.w, sv1.x, sv1.y, sv1.z, sv1.w};
    #pragma unroll
    for (int j = 0; j < 8; ++j) {
      const unsigned int z = (qzv >> SH[j]) & 15u;
      zz[j] = z * 0x10001u + 0x64006400u;
      ss[j] = __builtin_bit_cast(unsigned int, __builtin_amdgcn_cvt_pkrtz(svf[j], svf[j]));
    }
  };

  unsigned int qwc[4], qwn[4];
  auto loadQW = [&](unsigned int* dst, int k0) {
    #pragma unroll
    for (int i = 0; i < 4; ++i)
      dst[i] = (unsigned int)QW[(size_t)(k0 + dq_k + i) * NPACK + p0 + dq_p];
  };

  auto dequantWriteB = [&](int buf, const unsigned int* qw) {
    #pragma unroll
    for (int j = 0; j < 8; ++j) {
      const int sh = SH[j];
      const unsigned int q01 =
          ((qw[0] >> sh) & 15u) | (((qw[1] >> sh) & 15u) << 16) | 0x64006400u;
      const unsigned int q23 =
          ((qw[2] >> sh) & 15u) | (((qw[3] >> sh) & 15u) << 16) | 0x64006400u;
      const h2 w01 = (__builtin_bit_cast(h2, q01) - __builtin_bit_cast(h2, zz[j])) *
                     __builtin_bit_cast(h2, ss[j]);
      const h2 w23 = (__builtin_bit_cast(h2, q23) - __builtin_bit_cast(h2, zz[j])) *
                     __builtin_bit_cast(h2, ss[j]);
      uint2 wb;
      wb.x = __builtin_bit_cast(unsigned int, w01);
      wb.y = __builtin_bit_cast(unsigned int, w23);
      const unsigned int nn = dq_p * 8 + j;
      *(uint2*)((char*)&Blds[buf][0] + nn * 128 + ((dq_k * 2) ^ (swz(nn) << 4))) = wb;
    }
  };

  stageA(0, 0);
  prepGroup(0);
  loadQW(qwc, 0);
  dequantWriteB(0, qwc);
  loadQW(qwn, BK);
  __syncthreads();

  int cur = 0;
  for (int t = 0; t < NT; ++t) {
    if (t + 1 < NT) {
      const int kn = (t + 1) * BK;
      stageA(cur ^ 1, kn);
      if (((t + 1) & 1) == 0) prepGroup((t + 1) >> 1);
      dequantWriteB(cur ^ 1, qwn);
      if (t + 2 < NT) loadQW(qwn, kn + BK);
    }
    const char* Ac = (const char*)&Alds[cur][0];
    const char* Bc = (const char*)&Blds[cur][0];
    #pragma unroll
    for (int kk = 0; kk < 2; ++kk) {
      f16x8 afv[8], bfv[4];
      #pragma unroll
      for (int m = 0; m < 8; ++m) {
        const unsigned int r = (unsigned)(wr * 128 + m * 16 + l15);
        afv[m] = *(const f16x8*)(Ac + r * 128 + (((unsigned)(kk * 4 + l4) ^ swz(r)) << 4));
      }
      #pragma unroll
      for (int n = 0; n < 4; ++n) {
        const unsigned int r = (unsigned)(wc * 64 + n * 16 + l15);
        bfv[n] = *(const f16x8*)(Bc + r * 128 + (((unsigned)(kk * 4 + l4) ^ swz(r)) << 4));
      }
      #pragma unroll
      for (int m = 0; m < 8; ++m)
        #pragma unroll
        for (int n = 0; n < 4; ++n)
          acc[m][n] = __builtin_amdgcn_mfma_f32_16x16x32_f16(afv[m], bfv[n], acc[m][n], 0, 0, 0);
    }
    __syncthreads();
    cur ^= 1;
  }

  #pragma unroll
  for (int n = 0; n < 4; ++n) {
    const int col = n0 + wc * 64 + n * 16 + l15;
    const float bz = BIAS[col];
    #pragma unroll
    for (int m = 0; m < 8; ++m) {
      const int rbase = row0 + wr * 128 + m * 16 + l4 * 4;
      #pragma unroll
      for (int r = 0; r < 4; ++r) {
        OUT[(size_t)(rbase + r) * N_DIM + col] = acc[m][n][r] + bz;
      }
    }
  }
}

extern "C" void kernel_launch(void* const* d_in, const int* in_sizes, int n_in,
                              void* d_out, int out_size, void* d_ws, size_t ws_size,
                              hipStream_t stream) {
  const float* x = nullptr; const int* qw = nullptr; const int* qz = nullptr;
  const float* s = nullptr; const float* b = nullptr;
  for (int i = 0; i < n_in; ++i) {
    switch (in_sizes[i]) {
      case M_DIM * K_DIM:   x  = (const float*)d_in[i]; break;
      case K_DIM * NPACK:   qw = (const int*)d_in[i];   break;
      case NGROUPS * NPACK: qz = (const int*)d_in[i];   break;
      case NGROUPS * N_DIM: s  = (const float*)d_in[i]; break;
      case N_DIM:           b  = (const float*)d_in[i]; break;
    }
  }
  float* out = (float*)d_out;

  dim3 grid(N_DIM / BN, M_DIM / BM);  // 43 x 4 = 172
  const size_t xh_bytes = (size_t)M_DIM * K_DIM * 2;
  if (ws_size >= xh_bytes) {
    unsigned short* xh = (unsigned short*)d_ws;
    conv_x<<<(M_DIM * K_DIM) / (256 * 8), 256, 0, stream>>>(x, xh);
    awq_gemm8<<<grid, dim3(512), 0, stream>>>(xh, qw, qz, s, b, out);
  } else {
    awq_gemm_fb<<<grid, dim3(512), 0, stream>>>(x, qw, qz, s, b, out);
  }
}